// Round 15
// baseline (236.292 us; speedup 1.0000x reference)
//
#include <hip/hip_runtime.h>
#include <math.h>

#define H 2048
#define E 64
#define MR 16        // rows per block
#define NKS 64       // 32-wide k steps (full K per wave)

typedef _Float16 half8  __attribute__((ext_vector_type(8)));
typedef float    f32x4  __attribute__((ext_vector_type(4)));

#define MFMA16(A,B,C) __builtin_amdgcn_mfma_f32_16x16x32_f16(A,B,C,0,0,0)

// ws layout: Bh[H*E f16] | Bl[H*E f16] | csum[E f32] | bsum[E f32]

// Fused prep: pack W' = lnw*W into MFMA B-fragment layout (hi/lo f16 planes,
// lo scaled by 2048)  +  per-expert csum/bsum reductions. Grid = 64.
// Verified numerics-neutral in R6-R13.
__global__ __launch_bounds__(256) void prep_fused(const float* __restrict__ W,
        const float* __restrict__ lnw, const float* __restrict__ lnb,
        _Float16* __restrict__ Bh, _Float16* __restrict__ Bl,
        float* __restrict__ csum, float* __restrict__ bsum) {
    // ---- pack part ----
    {
        int idx  = blockIdx.x * 256 + threadIdx.x;      // 0..16383
        int lane = idx & 63;
        int e  = ((idx >> 6) & 3) * 16 + (lane & 15);
        int k0 = (idx >> 8) * 32 + ((lane >> 4) << 3);
        half8 hh, ll;
        #pragma unroll
        for (int j = 0; j < 8; ++j) {
            float wf = lnw[k0 + j] * W[e * H + k0 + j];
            _Float16 h = (_Float16)wf;
            _Float16 l = (_Float16)((wf - (float)h) * 2048.0f);
            hh[j] = h; ll[j] = l;
        }
        *(half8*)&Bh[(long)idx * 8] = hh;
        *(half8*)&Bl[(long)idx * 8] = ll;
    }
    // ---- sums part (expert = blockIdx.x) ----
    {
        __shared__ float rc[256], rb[256];
        int e = blockIdx.x, t = threadIdx.x;
        float cs = 0.f, bs = 0.f;
        #pragma unroll
        for (int j = 0; j < 8; ++j) {
            int k = t + j * 256;
            float w = W[e * H + k];
            cs += lnw[k] * w;
            bs += lnb[k] * w;
        }
        rc[t] = cs; rb[t] = bs;
        __syncthreads();
        for (int s = 128; s > 0; s >>= 1) {
            if (t < s) { rc[t] += rc[t + s]; rb[t] += rb[t + s]; }
            __syncthreads();
        }
        if (t == 0) { csum[e] = rc[0]; bsum[e] = rb[0]; }
    }
}

// Barrier-free streaming router. Wave = (16 rows x 16-expert tile et), full K.
// A-fragments are lane-local: lane l reads 32 contiguous bytes of row (l&15)
// at k = ks*32 + (l>>4)*8 straight from global (L1-shared across the 4 waves),
// converts to f16 hi/lo in-register, and runs the SAME ks-sequential 3-MFMA
// chain as R12 over the full K -> every logit is computed by one thread in
// the bit-identical verified order. No LDS, no barriers in the main loop.
// X prefetch 2 ks-steps deep, W 1 step deep; per-iteration issue order is
// W-then-X so the MFMA's W-wait (vmcnt FIFO) never drains the X prefetch.
// Register budget ~54 live (X 16 + W 16 + acc 8 + addr/stats ~14) to stay
// under this toolchain's hard 64-VGPR operating point (R13 lesson).
__global__ __launch_bounds__(256) void router_kernel(
    const float* __restrict__ X, const _Float16* __restrict__ Bh,
    const _Float16* __restrict__ Bl, const float* __restrict__ csum,
    const float* __restrict__ bsum, float* __restrict__ out, int nRows)
{
    __shared__ float C2[MR][E + 4];          // 4,352 B (epilogue only)

    const int t    = threadIdx.x;
    const int lane = t & 63;
    const int et   = t >> 6;                 // wave -> expert tile
    const int q    = lane >> 4;
    const int ln16 = lane & 15;
    const long rowBase = (long)blockIdx.x * MR;
    const long iOff = (long)nRows * 2;
    const long lOff = (long)nRows * 4;

    // lane-local A source: row (rowBase+ln16), float4 col q*2 within each ks
    const float4* Xp = (const float4*)X + (rowBase + ln16) * 512 + q * 2;
    // W fragment base (half8 units): frag (gks,et) at gks*256 + et*64 + lane
    const half8* BhP = (const half8*)Bh + et * 64 + lane;
    const half8* BlP = (const half8*)Bl + et * 64 + lane;

    f32x4 acc0 = (f32x4)0.f;
    f32x4 acc1 = (f32x4)0.f;
    float sacc = 0.f, qacc = 0.f;

// convert two float4 into Ah/Al (hi/lo split) + accumulate LN stats
#define CVT8(V0, V1, AH, AL) { \
    float4 v0_ = (V0), v1_ = (V1); \
    sacc += v0_.x + v0_.y + v0_.z + v0_.w + v1_.x + v1_.y + v1_.z + v1_.w; \
    qacc += v0_.x*v0_.x + v0_.y*v0_.y + v0_.z*v0_.z + v0_.w*v0_.w \
          + v1_.x*v1_.x + v1_.y*v1_.y + v1_.z*v1_.z + v1_.w*v1_.w; \
    _Float16 h0_ = (_Float16)v0_.x, h1_ = (_Float16)v0_.y, \
             h2_ = (_Float16)v0_.z, h3_ = (_Float16)v0_.w, \
             h4_ = (_Float16)v1_.x, h5_ = (_Float16)v1_.y, \
             h6_ = (_Float16)v1_.z, h7_ = (_Float16)v1_.w; \
    AH[0] = h0_; AH[1] = h1_; AH[2] = h2_; AH[3] = h3_; \
    AH[4] = h4_; AH[5] = h5_; AH[6] = h6_; AH[7] = h7_; \
    AL[0] = (_Float16)((v0_.x - (float)h0_) * 2048.f); \
    AL[1] = (_Float16)((v0_.y - (float)h1_) * 2048.f); \
    AL[2] = (_Float16)((v0_.z - (float)h2_) * 2048.f); \
    AL[3] = (_Float16)((v0_.w - (float)h3_) * 2048.f); \
    AL[4] = (_Float16)((v1_.x - (float)h4_) * 2048.f); \
    AL[5] = (_Float16)((v1_.y - (float)h5_) * 2048.f); \
    AL[6] = (_Float16)((v1_.z - (float)h6_) * 2048.f); \
    AL[7] = (_Float16)((v1_.w - (float)h7_) * 2048.f); }

    // prologue: X(ks0), X(ks1), W(ks0) in flight
    float4 xA0 = Xp[0], xA1 = Xp[1];
    float4 xB0 = Xp[8], xB1 = Xp[9];
    half8 wAh = BhP[0], wAl = BlP[0];
    half8 wBh, wBl;

    for (int ks = 0; ks < NKS; ks += 2) {
        // ---- even step: consume xA/wA; issue W(ks+1) then X(ks+2) ----
        {
            wBh = BhP[(ks + 1) * 256];
            wBl = BlP[(ks + 1) * 256];
            half8 Ah, Al;
            CVT8(xA0, xA1, Ah, Al)
            if (ks + 2 < NKS) {
                xA0 = Xp[(ks + 2) * 8];
                xA1 = Xp[(ks + 2) * 8 + 1];
            }
            acc0 = MFMA16(Ah, wAh, acc0);
            acc1 = MFMA16(Ah, wAl, acc1);
            acc1 = MFMA16(Al, wAh, acc1);
        }
        // ---- odd step: consume xB/wB; issue W(ks+2) then X(ks+3) ----
        {
            if (ks + 2 < NKS) {
                wAh = BhP[(ks + 2) * 256];
                wAl = BlP[(ks + 2) * 256];
            }
            half8 Ah, Al;
            CVT8(xB0, xB1, Ah, Al)
            if (ks + 3 < NKS) {
                xB0 = Xp[(ks + 3) * 8];
                xB1 = Xp[(ks + 3) * 8 + 1];
            }
            acc0 = MFMA16(Ah, wBh, acc0);
            acc1 = MFMA16(Ah, wBl, acc1);
            acc1 = MFMA16(Al, wBh, acc1);
        }
    }

    // ---- LN stats, fully in-register: lane l holds partial of row (l&15)
    // over cols q*8..; xor-16/32 completes each row within its q-group.
    sacc += __shfl_xor(sacc, 16);
    sacc += __shfl_xor(sacc, 32);
    qacc += __shfl_xor(qacc, 16);
    qacc += __shfl_xor(qacc, 32);
    // lane l now holds row (l&15) sums; fetch stats for this thread's 4 D rows
    float mu4[4], rs4[4];
    #pragma unroll
    for (int reg = 0; reg < 4; ++reg) {
        int r = q * 4 + reg;
        float s  = __shfl(sacc, r);
        float qq = __shfl(qacc, r);
        float mu = s * (1.f / H);
        mu4[reg] = mu;
        rs4[reg] = rsqrtf(qq * (1.f / H) - mu * mu + 1e-5f);
    }

    // ---- epilogue: combine splits, LN rank-1 correction, clip, write logits ----
    {
        int n = et * 16 + ln16;
        float cs = csum[n], bs = bsum[n];
        #pragma unroll
        for (int reg = 0; reg < 4; ++reg) {
            int r = q * 4 + reg;
            float raw = acc0[reg] + acc1[reg] * (1.f / 2048.f);
            float lg = rs4[reg] * (raw - mu4[reg] * cs) + bs;
            lg = fminf(fmaxf(lg, -10.f), 10.f);
            out[lOff + (rowBase + r) * 64 + n] = lg;
            C2[r][n] = lg;
        }
    }
    __syncthreads();   // the only barrier

    // ---- softmax + top2: wave et handles rows et*4 .. et*4+3 ----
    #pragma unroll
    for (int rr = 0; rr < 4; ++rr) {
        int r = et * 4 + rr;
        float l = C2[r][lane];
        float m = l;
        #pragma unroll
        for (int d = 1; d < 64; d <<= 1) m = fmaxf(m, __shfl_xor(m, d));
        float p = __expf(l - m);
        float ssum = p;
        #pragma unroll
        for (int d = 1; d < 64; d <<= 1) ssum += __shfl_xor(ssum, d);
        float prob = fminf(fmaxf(p / ssum, 1e-4f), 1.0f);

        float v1 = prob; int i1 = lane;
        #pragma unroll
        for (int d = 1; d < 64; d <<= 1) {
            float ov = __shfl_xor(v1, d);
            int   oi = __shfl_xor(i1, d);
            if (ov > v1 || (ov == v1 && oi < i1)) { v1 = ov; i1 = oi; }
        }
        float v2 = (lane == i1) ? -1.f : prob; int i2 = lane;
        #pragma unroll
        for (int d = 1; d < 64; d <<= 1) {
            float ov = __shfl_xor(v2, d);
            int   oi = __shfl_xor(i2, d);
            if (ov > v2 || (ov == v2 && oi < i2)) { v2 = ov; i2 = oi; }
        }
        if (lane == 0) {
            float ps = fmaxf(v1 + v2, 1e-4f);
            long rg_ = rowBase + r;
            out[rg_ * 2 + 0] = v1 / ps;
            out[rg_ * 2 + 1] = v2 / ps;
            out[iOff + rg_ * 2 + 0] = (float)i1;
            out[iOff + rg_ * 2 + 1] = (float)i2;
        }
    }
}

extern "C" void kernel_launch(void* const* d_in, const int* in_sizes, int n_in,
                              void* d_out, int out_size, void* d_ws, size_t ws_size,
                              hipStream_t stream) {
    const float* X   = (const float*)d_in[0];
    const float* lnw = (const float*)d_in[1];
    const float* lnb = (const float*)d_in[2];
    const float* W   = (const float*)d_in[3];
    float* outp = (float*)d_out;

    _Float16* Bh = (_Float16*)d_ws;
    _Float16* Bl = Bh + H * E;
    float* csum  = (float*)(Bl + H * E);
    float* bsum  = csum + E;

    int N = in_sizes[0] / H;                 // 16384 rows

    prep_fused<<<64, 256, 0, stream>>>(W, lnw, lnb, Bh, Bl, csum, bsum);
    router_kernel<<<N / MR, 256, 0, stream>>>(X, Bh, Bl, csum, bsum, outp, N);
}